// Round 6
// baseline (406.046 us; speedup 1.0000x reference)
//
#include <hip/hip_runtime.h>

// SoftRoutedLoRALinear on MI355X — augmented-K f16 MFMA GEMM.
// out[m,n] = sum_k Xa[m,k]*Wa[n,k] + bias[n],  K = 4096 + 128 (LoRA tail)
//   Xa tail[m, e*16+r] = 2*router[b,e] * sum_i x[m,i]*lora_A[e,r,i]
//   Wa tail[n, e*16+r] = lora_B[e,n,r]
// Main GEMM: m201-faithful 8-phase: 256x256 tile, BK=64, 8 waves, phases split
// by K-half, K-half staging (1 half/phase), vmcnt(4) at P2/P4 only (never
// drains), LDS [dbuf][kh][256][32] with slot^=(row>>1)&3 swizzle, setprio.

typedef _Float16 half8 __attribute__((ext_vector_type(8)));
typedef _Float16 half4 __attribute__((ext_vector_type(4)));
typedef float    f32x4 __attribute__((ext_vector_type(4)));

#define M_TOT 8192
#define N_TOT 4096
#define K_IN  4096
#define KA    4224
#define NT    66      // KA / 64

__device__ __forceinline__ void cvt_store4(_Float16* p, float4 f) {
  half4 h;
  h[0] = (_Float16)f.x; h[1] = (_Float16)f.y;
  h[2] = (_Float16)f.z; h[3] = (_Float16)f.w;
  *(half4*)p = h;
}

// ---------------- prep: f32 -> f16, compile-time source cols (no runtime div)
template <int LOG2C, int DCOLS>
__global__ __launch_bounds__(256) void convert_f32_f16_t(
    const float* __restrict__ src, _Float16* __restrict__ dst, int total8) {
  for (int i = blockIdx.x * 256 + threadIdx.x; i < total8;
       i += gridDim.x * 256) {
    int base = i << 3;
    int r = base >> LOG2C;
    int c = base & ((1 << LOG2C) - 1);
    const float4* s = (const float4*)(src + (size_t)base);
    float4 f0 = s[0], f1 = s[1];
    half8 h;
    h[0]=(_Float16)f0.x; h[1]=(_Float16)f0.y; h[2]=(_Float16)f0.z; h[3]=(_Float16)f0.w;
    h[4]=(_Float16)f1.x; h[5]=(_Float16)f1.y; h[6]=(_Float16)f1.z; h[7]=(_Float16)f1.w;
    *(half8*)(dst + (size_t)r * DCOLS + c) = h;
  }
}

// ---------------- prep: lora_B -> Wa tail (f16)
__global__ __launch_bounds__(256) void wtail_gather_f16(
    const float* __restrict__ loraB, _Float16* __restrict__ Wa) {
  int idx = blockIdx.x * 256 + threadIdx.x;       // 0 .. 4096*128-1
  int n = idx >> 7, j = idx & 127;
  int e = j >> 4, r = j & 15;
  Wa[(size_t)n * KA + K_IN + j] =
      (_Float16)loraB[((size_t)e * N_TOT + n) * 16 + r];
}

// ---------------- prep (fallback): lora_B -> fp32 [4096][128]
__global__ __launch_bounds__(256) void lorabf_gather_f32(
    const float* __restrict__ loraB, float* __restrict__ lorabf) {
  int idx = blockIdx.x * 256 + threadIdx.x;
  int n = idx >> 7, j = idx & 127;
  int e = j >> 4, r = j & 15;
  lorabf[(size_t)n * 128 + j] = loraB[((size_t)e * N_TOT + n) * 16 + r];
}

// ---------------- fast-path mid: reads f16 Xa + f16 loraA, writes f16 Xa tail
__global__ __launch_bounds__(256) void mid2_kernel(
    _Float16* __restrict__ Xa, const _Float16* __restrict__ lAh,
    const float* __restrict__ router) {
  __shared__ _Float16 As[32 * 64];    // 4 KB
  __shared__ _Float16 Bs[128 * 64];   // 16 KB
  int tid = threadIdx.x, lane = tid & 63, w = tid >> 6;
  int m0 = blockIdx.x * 32;
  int b = m0 >> 11;
  f32x4 acc[2][2] = {};

  for (int ks = 0; ks < 64; ++ks) {
    int kb = ks * 128;   // byte offset, 64 f16
    {
      const char* s = (const char*)Xa +
          (size_t)(m0 + w * 8 + (lane >> 3)) * (KA * 2) + kb + (lane & 7) * 16;
      __builtin_amdgcn_global_load_lds(
          (const __attribute__((address_space(1))) void*)s,
          (__attribute__((address_space(3))) void*)((char*)As + w * 1024), 16, 0, 0);
    }
#pragma unroll
    for (int i = 0; i < 4; ++i) {
      const char* s = (const char*)lAh +
          (size_t)((w * 4 + i) * 8 + (lane >> 3)) * (4096 * 2) + kb + (lane & 7) * 16;
      __builtin_amdgcn_global_load_lds(
          (const __attribute__((address_space(1))) void*)s,
          (__attribute__((address_space(3))) void*)((char*)Bs + (w * 4 + i) * 1024), 16, 0, 0);
    }
    __syncthreads();
#pragma unroll
    for (int kk = 0; kk < 2; ++kk) {
      half8 a[2], bf[2];
#pragma unroll
      for (int mi = 0; mi < 2; ++mi)
        a[mi] = *(const half8*)(As + (mi * 16 + (lane & 15)) * 64 + kk * 32 + (lane >> 4) * 8);
#pragma unroll
      for (int ni = 0; ni < 2; ++ni)
        bf[ni] = *(const half8*)(Bs + (w * 32 + ni * 16 + (lane & 15)) * 64 + kk * 32 + (lane >> 4) * 8);
#pragma unroll
      for (int mi = 0; mi < 2; ++mi)
#pragma unroll
        for (int ni = 0; ni < 2; ++ni)
          acc[mi][ni] = __builtin_amdgcn_mfma_f32_16x16x32_f16(a[mi], bf[ni], acc[mi][ni], 0, 0, 0);
    }
    __syncthreads();
  }

#pragma unroll
  for (int ni = 0; ni < 2; ++ni) {
    int j = w * 32 + ni * 16 + (lane & 15);
    int e = j >> 4;
    float sc = 2.0f * router[b * 8 + e];
#pragma unroll
    for (int mi = 0; mi < 2; ++mi) {
      f32x4 v = acc[mi][ni];
#pragma unroll
      for (int jj = 0; jj < 4; ++jj) {
        int m = m0 + mi * 16 + (lane >> 4) * 4 + jj;
        Xa[(size_t)m * KA + K_IN + j] = (_Float16)(v[jj] * sc);
      }
    }
  }
}

// ---------------- fallback mid (f32 sources -> f32 midw)
__global__ __launch_bounds__(256) void mid_kernel(
    const float* __restrict__ x, const float* __restrict__ loraA,
    const float* __restrict__ router, float* __restrict__ midw) {
  __shared__ _Float16 As[32 * 64];
  __shared__ _Float16 Bs[128 * 64];
  int tid = threadIdx.x, lane = tid & 63, w = tid >> 6;
  int m0 = blockIdx.x * 32;
  int b = m0 >> 11;
  f32x4 acc[2][2] = {};
  for (int ks = 0; ks < 64; ++ks) {
    int k0 = ks * 64;
#pragma unroll
    for (int it = 0; it < 2; ++it) {
      int idx = tid + it * 256;
      int r = idx >> 4, c4 = idx & 15;
      float4 f = *(const float4*)(x + (size_t)(m0 + r) * K_IN + k0 + c4 * 4);
      cvt_store4(As + r * 64 + c4 * 4, f);
    }
#pragma unroll
    for (int it = 0; it < 8; ++it) {
      int idx = tid + it * 256;
      int r = idx >> 4, c4 = idx & 15;
      float4 f = *(const float4*)(loraA + (size_t)r * K_IN + k0 + c4 * 4);
      cvt_store4(Bs + r * 64 + c4 * 4, f);
    }
    __syncthreads();
#pragma unroll
    for (int kk = 0; kk < 2; ++kk) {
      half8 a[2], bf[2];
#pragma unroll
      for (int mi = 0; mi < 2; ++mi)
        a[mi] = *(const half8*)(As + (mi * 16 + (lane & 15)) * 64 + kk * 32 + (lane >> 4) * 8);
#pragma unroll
      for (int ni = 0; ni < 2; ++ni)
        bf[ni] = *(const half8*)(Bs + (w * 32 + ni * 16 + (lane & 15)) * 64 + kk * 32 + (lane >> 4) * 8);
#pragma unroll
      for (int mi = 0; mi < 2; ++mi)
#pragma unroll
        for (int ni = 0; ni < 2; ++ni)
          acc[mi][ni] = __builtin_amdgcn_mfma_f32_16x16x32_f16(a[mi], bf[ni], acc[mi][ni], 0, 0, 0);
    }
    __syncthreads();
  }
#pragma unroll
  for (int ni = 0; ni < 2; ++ni) {
    int j = w * 32 + ni * 16 + (lane & 15);
    int e = j >> 4;
    float sc = 2.0f * router[b * 8 + e];
#pragma unroll
    for (int mi = 0; mi < 2; ++mi) {
      f32x4 v = acc[mi][ni];
#pragma unroll
      for (int jj = 0; jj < 4; ++jj) {
        int m = m0 + mi * 16 + (lane >> 4) * 4 + jj;
        midw[(size_t)m * 128 + j] = v[jj] * sc;
      }
    }
  }
}

// ====== main GEMM: 256x256, BK=64, 8 waves, kk-split 8-phase (m201 port) ====
#define BAR    __builtin_amdgcn_s_barrier()
#define SCHED0 __builtin_amdgcn_sched_barrier(0)
#define PRIO1  __builtin_amdgcn_s_setprio(1)
#define PRIO0  __builtin_amdgcn_s_setprio(0)
#define LGKM0  do { asm volatile("s_waitcnt lgkmcnt(0)" ::: "memory"); \
                    __builtin_amdgcn_sched_barrier(0); } while (0)
#define VMW4   asm volatile("s_waitcnt vmcnt(4)" ::: "memory")
#define VMW0   asm volatile("s_waitcnt vmcnt(0)" ::: "memory")
#define GLOAD(src, dst) __builtin_amdgcn_global_load_lds( \
    (const __attribute__((address_space(1))) void*)(src), \
    (__attribute__((address_space(3))) void*)(dst), 16, 0, 0)

// stage one K-half (256 rows x 32 f16) of tile t1 into plane (2 gloads/thread)
#define STAGEH(srcbase, t1, kh, plane) do { \
  const char* s_ = (srcbase) + (size_t)(t1) * 128 + (kh) * 64; \
  GLOAD(s_ + goff0, (char*)(plane) + loff0); \
  GLOAD(s_ + goff1, (char*)(plane) + loff1); \
  } while (0)

// read 4 A-frags (rows wm+(mb..mb+3)*16) from a kh plane
#define READ_A4(aF, mb, plane) do { \
  _Pragma("unroll") for (int mi = 0; mi < 4; ++mi) \
    aF[mi] = *(const half8*)((const char*)(plane) + \
                             (wm + ((mb) + mi) * 16 + ln15) * 64 + rslot); \
  } while (0)

// read 4 B-frags (rows wn+0..63) from a kh plane
#define READ_B4(bF, plane) do { \
  _Pragma("unroll") for (int ni = 0; ni < 4; ++ni) \
    bF[ni] = *(const half8*)((const char*)(plane) + \
                             (wn + ni * 16 + ln15) * 64 + rslot); \
  } while (0)

// 16 MFMA: quadrant rows (mb..mb+3), all 4 ni, one K=32 half
#define MFMA_Q16(aF, bF, mb) do { \
  PRIO1; \
  _Pragma("unroll") for (int mi = 0; mi < 4; ++mi) \
    _Pragma("unroll") for (int ni = 0; ni < 4; ++ni) \
      acc[(mb) + mi][ni] = __builtin_amdgcn_mfma_f32_16x16x32_f16( \
          aF[mi], bF[ni], acc[(mb) + mi][ni], 0, 0, 0); \
  PRIO0; \
  } while (0)

__global__ __launch_bounds__(512, 2) void gemm256(
    const _Float16* __restrict__ Xa, const _Float16* __restrict__ Wa,
    const float* __restrict__ bias, float* __restrict__ out) {
  // [dbuf][kh][256 rows][32 f16]; rows are 64B, 4 slots of 16B, swizzled.
  __shared__ _Float16 As[2][2][256 * 32];   // 64 KB
  __shared__ _Float16 Bs[2][2][256 * 32];   // 64 KB

  int tid = threadIdx.x, lane = tid & 63, w = tid >> 6;
  int ln15 = lane & 15, ln4 = lane >> 4;
  int wm = (w >> 2) * 128, wn = (w & 3) * 64;

  // T1: XCD chunk swizzle — 512 blocks = 8 XCDs x 64; each XCD an 8x8 chunk.
  int bid = blockIdx.x;
  int xcd = bid & 7, idx = bid >> 3;
  int mt = (xcd & 3) * 8 + (idx & 7);
  int nt = (xcd >> 2) * 8 + (idx >> 3);
  int m0 = mt << 8, n0 = nt << 8;

  const char* XpC = (const char*)Xa + (size_t)m0 * (KA * 2);
  const char* WpC = (const char*)Wa + (size_t)n0 * (KA * 2);

  // Staging: instr (w,j) covers rows (2w+j)*16..+15 of the half.
  // lane -> row (lane>>2), slot (lane&3); source pre-swizzle slot^=(row>>1)&3.
  int sslot16 = (((lane & 3) ^ ((lane >> 3) & 3)) * 16);
  int goff0 = ((2 * w + 0) * 16 + (lane >> 2)) * (KA * 2) + sslot16;
  int goff1 = ((2 * w + 1) * 16 + (lane >> 2)) * (KA * 2) + sslot16;
  int loff0 = (2 * w + 0) * 1024 + lane * 16;
  int loff1 = (2 * w + 1) * 1024 + lane * 16;

  // Fragment read: row*64 + (ln4 ^ ((row>>1)&3))*16; (row>>1)&3 == (lane>>1)&3.
  int rslot = ((ln4 ^ ((lane >> 1) & 3)) * 16);

  f32x4 acc[8][4] = {};
  half8 aF[4], bF[4];

  // prologue: stage tile 0 (4 halves), drain once, publish.
  STAGEH(XpC, 0, 0, As[0][0]); STAGEH(WpC, 0, 0, Bs[0][0]);
  STAGEH(XpC, 0, 1, As[0][1]); STAGEH(WpC, 0, 1, Bs[0][1]);
  VMW0; BAR; SCHED0;

#pragma unroll 1
  for (int t = 0; t < NT; ++t) {
    int cur = t & 1, nxt = cur ^ 1;
    bool pf = (t < NT - 1);

    // P1 (kh0, rows 0-3): 8 reads; stage A-kh0(t+1)
    READ_A4(aF, 0, As[cur][0]);
    READ_B4(bF, Bs[cur][0]);
    if (pf) STAGEH(XpC, t + 1, 0, As[nxt][0]);
    BAR; LGKM0; MFMA_Q16(aF, bF, 0); BAR;

    // P2 (kh0, rows 4-7): 4 reads; stage B-kh0(t+1); guard kh1(t)
    READ_A4(aF, 4, As[cur][0]);
    if (pf) STAGEH(WpC, t + 1, 0, Bs[nxt][0]);
    BAR; LGKM0; MFMA_Q16(aF, bF, 4);
    if (pf) { VMW4; } else { VMW0; }
    BAR; SCHED0;

    // P3 (kh1, rows 0-3): 8 reads; stage A-kh1(t+1)
    READ_A4(aF, 0, As[cur][1]);
    READ_B4(bF, Bs[cur][1]);
    if (pf) STAGEH(XpC, t + 1, 1, As[nxt][1]);
    BAR; LGKM0; MFMA_Q16(aF, bF, 0); BAR;

    // P4 (kh1, rows 4-7): 4 reads; stage B-kh1(t+1); guard kh0(t+1)
    READ_A4(aF, 4, As[cur][1]);
    if (pf) STAGEH(WpC, t + 1, 1, Bs[nxt][1]);
    BAR; LGKM0; MFMA_Q16(aF, bF, 4);
    if (pf) { VMW4; BAR; SCHED0; }
  }

  // epilogue: + bias, fp32 store. C/D: col = lane&15, row = (lane>>4)*4 + reg
#pragma unroll
  for (int ni = 0; ni < 4; ++ni) {
    int n = n0 + wn + ni * 16 + ln15;
    float bz = bias[n];
#pragma unroll
    for (int mi = 0; mi < 8; ++mi) {
      f32x4 v = acc[mi][ni];
      int mb = m0 + wm + mi * 16 + ln4 * 4;
#pragma unroll
      for (int jj = 0; jj < 4; ++jj)
        out[(size_t)(mb + jj) * N_TOT + n] = v[jj] + bz;
    }
  }
}

// ---------------- fallback GEMM (reg-staged f32->f16, 128x128, low ws)
__global__ __launch_bounds__(256) void gemm_fallback(
    const float* __restrict__ x, const float* __restrict__ wgt,
    const float* __restrict__ midw, const float* __restrict__ lorabf,
    const float* __restrict__ bias, float* __restrict__ out) {
  __shared__ _Float16 As[128 * 64];
  __shared__ _Float16 Bs[128 * 64];
  int tid = threadIdx.x, lane = tid & 63, w = tid >> 6;
  int mt = blockIdx.x & 63, nt = blockIdx.x >> 6;
  int m0 = mt << 7, n0 = nt << 7;
  int wm = (w >> 1) * 64, wn = (w & 1) * 64;
  f32x4 acc[4][4] = {};
  for (int ks = 0; ks < NT; ++ks) {
    int k0 = ks * 64;
    const float *asrc, *bsrc; size_t astr, bstr; int ac, bc;
    if (ks < 64) { asrc = x;    astr = K_IN; ac = k0;        bsrc = wgt;    bstr = K_IN; bc = k0; }
    else         { asrc = midw; astr = 128;  ac = k0 - K_IN; bsrc = lorabf; bstr = 128;  bc = k0 - K_IN; }
#pragma unroll
    for (int it = 0; it < 8; ++it) {
      int idx = tid + it * 256;
      int r = idx >> 4, c4 = idx & 15;
      float4 fa = *(const float4*)(asrc + (size_t)(m0 + r) * astr + ac + c4 * 4);
      cvt_store4(As + r * 64 + c4 * 4, fa);
      float4 fb = *(const float4*)(bsrc + (size_t)(n0 + r) * bstr + bc + c4 * 4);
      cvt_store4(Bs + r * 64 + c4 * 4, fb);
    }
    __syncthreads();
#pragma unroll
    for (int kk = 0; kk < 2; ++kk) {
      half8 a[4], bf[4];
#pragma unroll
      for (int mi = 0; mi < 4; ++mi)
        a[mi] = *(const half8*)(As + (wm + mi * 16 + (lane & 15)) * 64 + kk * 32 + (lane >> 4) * 8);
#pragma unroll
      for (int ni = 0; ni < 4; ++ni)
        bf[ni] = *(const half8*)(Bs + (wn + ni * 16 + (lane & 15)) * 64 + kk * 32 + (lane >> 4) * 8);
#pragma unroll
      for (int mi = 0; mi < 4; ++mi)
#pragma unroll
        for (int ni = 0; ni < 4; ++ni)
          acc[mi][ni] = __builtin_amdgcn_mfma_f32_16x16x32_f16(a[mi], bf[ni], acc[mi][ni], 0, 0, 0);
    }
    __syncthreads();
  }
#pragma unroll
  for (int ni = 0; ni < 4; ++ni) {
    int n = n0 + wn + ni * 16 + (lane & 15);
    float bz = bias[n];
#pragma unroll
    for (int mi = 0; mi < 4; ++mi) {
      f32x4 v = acc[mi][ni];
      int mbase = m0 + wm + mi * 16 + (lane >> 4) * 4;
#pragma unroll
      for (int jj = 0; jj < 4; ++jj)
        out[(size_t)(mbase + jj) * N_TOT + n] = v[jj] + bz;
    }
  }
}

extern "C" void kernel_launch(void* const* d_in, const int* in_sizes, int n_in,
                              void* d_out, int out_size, void* d_ws, size_t ws_size,
                              hipStream_t stream) {
  const float* x      = (const float*)d_in[0];
  const float* router = (const float*)d_in[1];
  const float* wgt    = (const float*)d_in[2];
  const float* bias   = (const float*)d_in[3];
  const float* loraA  = (const float*)d_in[4];
  const float* loraB  = (const float*)d_in[5];
  float* out = (float*)d_out;
  char* ws = (char*)d_ws;

  const size_t XAUG_B = (size_t)M_TOT * KA * 2;    // 69,206,016
  const size_t WAUG_B = (size_t)N_TOT * KA * 2;    // 34,603,008
  const size_t LAH_B  = (size_t)128 * K_IN * 2;    //  1,048,576
  const size_t MIDW_B = (size_t)M_TOT * 128 * 4;   //  4,194,304
  bool fast = ws_size >= XAUG_B + WAUG_B + LAH_B;

  if (fast) {
    _Float16* Xa  = (_Float16*)ws;
    _Float16* Wa  = (_Float16*)(ws + XAUG_B);
    _Float16* lAh = (_Float16*)(ws + XAUG_B + WAUG_B);
    convert_f32_f16_t<12, KA><<<2048, 256, 0, stream>>>(x,   Xa, M_TOT * K_IN / 8);
    convert_f32_f16_t<12, KA><<<2048, 256, 0, stream>>>(wgt, Wa, N_TOT * K_IN / 8);
    convert_f32_f16_t<12, 4096><<<256, 256, 0, stream>>>(loraA, lAh, 128 * K_IN / 8);
    wtail_gather_f16<<<2048, 256, 0, stream>>>(loraB, Wa);
    mid2_kernel<<<256, 256, 0, stream>>>(Xa, lAh, router);
    gemm256<<<512, 512, 0, stream>>>(Xa, Wa, bias, out);
  } else {
    float* midw   = (float*)ws;
    float* lorabf = (float*)(ws + MIDW_B);
    lorabf_gather_f32<<<2048, 256, 0, stream>>>(loraB, lorabf);
    mid_kernel<<<256, 256, 0, stream>>>(x, loraA, router, midw);
    gemm_fallback<<<2048, 256, 0, stream>>>(x, wgt, midw, lorabf, bias, out);
  }
}

// Round 7
// 377.022 us; speedup vs baseline: 1.0770x; 1.0770x over previous
//
#include <hip/hip_runtime.h>

// SoftRoutedLoRALinear on MI355X — augmented-K f16 MFMA GEMM.
// out[m,n] = sum_k Xa[m,k]*Wa[n,k] + bias[n],  K = 4096 + 128 (LoRA tail)
//   Xa tail[m, e*16+r] = 2*router[b,e] * sum_i x[m,i]*lora_A[e,r,i]
//   Wa tail[n, e*16+r] = lora_B[e,n,r]
// Main GEMM: 256x256 tile, BK=32, 8 waves, RING-4 K-tile pipeline:
// per tile {12 ds_read, 4 global_load_lds for t+3, lgkm0, 32 MFMA, vmcnt(8),
// barrier}. Stages land 3 phases before use (counted, never drains).
// T2 swizzle both-sides, T5 setprio, XCD chunk swizzle.

typedef _Float16 half8 __attribute__((ext_vector_type(8)));
typedef _Float16 half4 __attribute__((ext_vector_type(4)));
typedef float    f32x4 __attribute__((ext_vector_type(4)));

#define M_TOT 8192
#define N_TOT 4096
#define K_IN  4096
#define KA    4224
#define NT    132     // KA / 32

__device__ __forceinline__ void cvt_store4(_Float16* p, float4 f) {
  half4 h;
  h[0] = (_Float16)f.x; h[1] = (_Float16)f.y;
  h[2] = (_Float16)f.z; h[3] = (_Float16)f.w;
  *(half4*)p = h;
}

// ---------------- prep: f32 -> f16, compile-time source cols (no runtime div)
template <int LOG2C, int DCOLS>
__global__ __launch_bounds__(256) void convert_f32_f16_t(
    const float* __restrict__ src, _Float16* __restrict__ dst, int total8) {
  for (int i = blockIdx.x * 256 + threadIdx.x; i < total8;
       i += gridDim.x * 256) {
    int base = i << 3;
    int r = base >> LOG2C;
    int c = base & ((1 << LOG2C) - 1);
    const float4* s = (const float4*)(src + (size_t)base);
    float4 f0 = s[0], f1 = s[1];
    half8 h;
    h[0]=(_Float16)f0.x; h[1]=(_Float16)f0.y; h[2]=(_Float16)f0.z; h[3]=(_Float16)f0.w;
    h[4]=(_Float16)f1.x; h[5]=(_Float16)f1.y; h[6]=(_Float16)f1.z; h[7]=(_Float16)f1.w;
    *(half8*)(dst + (size_t)r * DCOLS + c) = h;
  }
}

// ---------------- prep: lora_B -> Wa tail (f16)
__global__ __launch_bounds__(256) void wtail_gather_f16(
    const float* __restrict__ loraB, _Float16* __restrict__ Wa) {
  int idx = blockIdx.x * 256 + threadIdx.x;       // 0 .. 4096*128-1
  int n = idx >> 7, j = idx & 127;
  int e = j >> 4, r = j & 15;
  Wa[(size_t)n * KA + K_IN + j] =
      (_Float16)loraB[((size_t)e * N_TOT + n) * 16 + r];
}

// ---------------- prep (fallback): lora_B -> fp32 [4096][128]
__global__ __launch_bounds__(256) void lorabf_gather_f32(
    const float* __restrict__ loraB, float* __restrict__ lorabf) {
  int idx = blockIdx.x * 256 + threadIdx.x;
  int n = idx >> 7, j = idx & 127;
  int e = j >> 4, r = j & 15;
  lorabf[(size_t)n * 128 + j] = loraB[((size_t)e * N_TOT + n) * 16 + r];
}

// ---------------- fast-path mid: reads f16 Xa + f16 loraA, writes f16 Xa tail
__global__ __launch_bounds__(256) void mid2_kernel(
    _Float16* __restrict__ Xa, const _Float16* __restrict__ lAh,
    const float* __restrict__ router) {
  __shared__ _Float16 As[32 * 64];    // 4 KB
  __shared__ _Float16 Bs[128 * 64];   // 16 KB
  int tid = threadIdx.x, lane = tid & 63, w = tid >> 6;
  int m0 = blockIdx.x * 32;
  int b = m0 >> 11;
  f32x4 acc[2][2] = {};

  for (int ks = 0; ks < 64; ++ks) {
    int kb = ks * 128;   // byte offset, 64 f16
    {
      const char* s = (const char*)Xa +
          (size_t)(m0 + w * 8 + (lane >> 3)) * (KA * 2) + kb + (lane & 7) * 16;
      __builtin_amdgcn_global_load_lds(
          (const __attribute__((address_space(1))) void*)s,
          (__attribute__((address_space(3))) void*)((char*)As + w * 1024), 16, 0, 0);
    }
#pragma unroll
    for (int i = 0; i < 4; ++i) {
      const char* s = (const char*)lAh +
          (size_t)((w * 4 + i) * 8 + (lane >> 3)) * (4096 * 2) + kb + (lane & 7) * 16;
      __builtin_amdgcn_global_load_lds(
          (const __attribute__((address_space(1))) void*)s,
          (__attribute__((address_space(3))) void*)((char*)Bs + (w * 4 + i) * 1024), 16, 0, 0);
    }
    __syncthreads();
#pragma unroll
    for (int kk = 0; kk < 2; ++kk) {
      half8 a[2], bf[2];
#pragma unroll
      for (int mi = 0; mi < 2; ++mi)
        a[mi] = *(const half8*)(As + (mi * 16 + (lane & 15)) * 64 + kk * 32 + (lane >> 4) * 8);
#pragma unroll
      for (int ni = 0; ni < 2; ++ni)
        bf[ni] = *(const half8*)(Bs + (w * 32 + ni * 16 + (lane & 15)) * 64 + kk * 32 + (lane >> 4) * 8);
#pragma unroll
      for (int mi = 0; mi < 2; ++mi)
#pragma unroll
        for (int ni = 0; ni < 2; ++ni)
          acc[mi][ni] = __builtin_amdgcn_mfma_f32_16x16x32_f16(a[mi], bf[ni], acc[mi][ni], 0, 0, 0);
    }
    __syncthreads();
  }

#pragma unroll
  for (int ni = 0; ni < 2; ++ni) {
    int j = w * 32 + ni * 16 + (lane & 15);
    int e = j >> 4;
    float sc = 2.0f * router[b * 8 + e];
#pragma unroll
    for (int mi = 0; mi < 2; ++mi) {
      f32x4 v = acc[mi][ni];
#pragma unroll
      for (int jj = 0; jj < 4; ++jj) {
        int m = m0 + mi * 16 + (lane >> 4) * 4 + jj;
        Xa[(size_t)m * KA + K_IN + j] = (_Float16)(v[jj] * sc);
      }
    }
  }
}

// ---------------- fallback mid (f32 sources -> f32 midw)
__global__ __launch_bounds__(256) void mid_kernel(
    const float* __restrict__ x, const float* __restrict__ loraA,
    const float* __restrict__ router, float* __restrict__ midw) {
  __shared__ _Float16 As[32 * 64];
  __shared__ _Float16 Bs[128 * 64];
  int tid = threadIdx.x, lane = tid & 63, w = tid >> 6;
  int m0 = blockIdx.x * 32;
  int b = m0 >> 11;
  f32x4 acc[2][2] = {};
  for (int ks = 0; ks < 64; ++ks) {
    int k0 = ks * 64;
#pragma unroll
    for (int it = 0; it < 2; ++it) {
      int idx = tid + it * 256;
      int r = idx >> 4, c4 = idx & 15;
      float4 f = *(const float4*)(x + (size_t)(m0 + r) * K_IN + k0 + c4 * 4);
      cvt_store4(As + r * 64 + c4 * 4, f);
    }
#pragma unroll
    for (int it = 0; it < 8; ++it) {
      int idx = tid + it * 256;
      int r = idx >> 4, c4 = idx & 15;
      float4 f = *(const float4*)(loraA + (size_t)r * K_IN + k0 + c4 * 4);
      cvt_store4(Bs + r * 64 + c4 * 4, f);
    }
    __syncthreads();
#pragma unroll
    for (int kk = 0; kk < 2; ++kk) {
      half8 a[2], bf[2];
#pragma unroll
      for (int mi = 0; mi < 2; ++mi)
        a[mi] = *(const half8*)(As + (mi * 16 + (lane & 15)) * 64 + kk * 32 + (lane >> 4) * 8);
#pragma unroll
      for (int ni = 0; ni < 2; ++ni)
        bf[ni] = *(const half8*)(Bs + (w * 32 + ni * 16 + (lane & 15)) * 64 + kk * 32 + (lane >> 4) * 8);
#pragma unroll
      for (int mi = 0; mi < 2; ++mi)
#pragma unroll
        for (int ni = 0; ni < 2; ++ni)
          acc[mi][ni] = __builtin_amdgcn_mfma_f32_16x16x32_f16(a[mi], bf[ni], acc[mi][ni], 0, 0, 0);
    }
    __syncthreads();
  }
#pragma unroll
  for (int ni = 0; ni < 2; ++ni) {
    int j = w * 32 + ni * 16 + (lane & 15);
    int e = j >> 4;
    float sc = 2.0f * router[b * 8 + e];
#pragma unroll
    for (int mi = 0; mi < 2; ++mi) {
      f32x4 v = acc[mi][ni];
#pragma unroll
      for (int jj = 0; jj < 4; ++jj) {
        int m = m0 + mi * 16 + (lane >> 4) * 4 + jj;
        midw[(size_t)m * 128 + j] = v[jj] * sc;
      }
    }
  }
}

// ====== main GEMM: 256x256, BK=32, 8 waves, RING-4 counted pipeline =========
#define BAR    __builtin_amdgcn_s_barrier()
#define SCHED0 __builtin_amdgcn_sched_barrier(0)
#define PRIO1  __builtin_amdgcn_s_setprio(1)
#define PRIO0  __builtin_amdgcn_s_setprio(0)
#define LGKM0  do { asm volatile("s_waitcnt lgkmcnt(0)" ::: "memory"); \
                    __builtin_amdgcn_sched_barrier(0); } while (0)
#define VMW8   asm volatile("s_waitcnt vmcnt(8)" ::: "memory")
#define VMW4   asm volatile("s_waitcnt vmcnt(4)" ::: "memory")
#define VMW0   asm volatile("s_waitcnt vmcnt(0)" ::: "memory")
#define GLOAD(src, dst) __builtin_amdgcn_global_load_lds( \
    (const __attribute__((address_space(1))) void*)(src), \
    (__attribute__((address_space(3))) void*)(dst), 16, 0, 0)

// A slot SL at LDS bytes [SL*16384, +16K); B at 65536 + SL*16384.
// Read: row*64 + (ln4 ^ ((row>>1)&3))*16 — 12 reads, all base+imm.
#define READS(SL) do { \
  _Pragma("unroll") for (int mi = 0; mi < 8; ++mi) \
    aF[mi] = *(const half8*)(LDS + (SL) * 16384 + \
                             (wm + mi * 16 + ln15) * 64 + rslot); \
  _Pragma("unroll") for (int ni = 0; ni < 4; ++ni) \
    bF[ni] = *(const half8*)(LDS + 65536 + (SL) * 16384 + \
                             (wn + ni * 16 + ln15) * 64 + rslot); \
  } while (0)

// stage K32-tile TT into ring slot SL (A:2 + B:2 gloads, linear LDS dest)
#define STAGE4(TT, SL) do { \
  const char* sA_ = XpC + (size_t)(TT) * 64; \
  const char* sB_ = WpC + (size_t)(TT) * 64; \
  GLOAD(sA_ + goff0, LDS + (SL) * 16384 + l0); \
  GLOAD(sA_ + goff1, LDS + (SL) * 16384 + l1); \
  GLOAD(sB_ + goff0, LDS + 65536 + (SL) * 16384 + l0); \
  GLOAD(sB_ + goff1, LDS + 65536 + (SL) * 16384 + l1); \
  } while (0)

#define MFMA32 do { \
  PRIO1; \
  _Pragma("unroll") for (int mi = 0; mi < 8; ++mi) \
    _Pragma("unroll") for (int ni = 0; ni < 4; ++ni) \
      acc[mi][ni] = __builtin_amdgcn_mfma_f32_16x16x32_f16( \
          aF[mi], bF[ni], acc[mi][ni], 0, 0, 0); \
  PRIO0; \
  } while (0)

// full steady-state tile: t = t4 + SL; stage t+3 into slot (SL+3)&3
#define TILE_FULL(SL) do { \
  READS(SL); \
  STAGE4(t4 + (SL) + 3, ((SL) + 3) & 3); \
  LGKM0; MFMA32; VMW8; BAR; SCHED0; \
  } while (0)

__global__ __launch_bounds__(512, 2) void gemm256(
    const _Float16* __restrict__ Xa, const _Float16* __restrict__ Wa,
    const float* __restrict__ bias, float* __restrict__ out) {
  __shared__ __align__(16) char LDS[131072];   // A ring 64K | B ring 64K

  int tid = threadIdx.x, lane = tid & 63, w = tid >> 6;
  int ln15 = lane & 15, ln4 = lane >> 4;
  int wm = (w >> 2) * 128, wn = (w & 3) * 64;

  // T1: XCD chunk swizzle — 512 blocks = 8 XCDs x 64; each XCD an 8x8 chunk.
  int bid = blockIdx.x;
  int xcd = bid & 7, idx = bid >> 3;
  int mt = (xcd & 3) * 8 + (idx & 7);
  int nt = (xcd >> 2) * 8 + (idx >> 3);
  int m0 = mt << 8, n0 = nt << 8;

  const char* XpC = (const char*)Xa + (size_t)m0 * (KA * 2);
  const char* WpC = (const char*)Wa + (size_t)n0 * (KA * 2);

  // Staging: idx = tid + j*512 -> row = idx>>2, slot4 = idx&3.
  // Source pre-swizzle slot4 ^= (row>>1)&3; LDS dest linear idx*16.
  int i0 = tid, i1 = tid + 512;
  int goff0 = (i0 >> 2) * (KA * 2) + (((i0 & 3) ^ ((i0 >> 3) & 3)) * 16);
  int goff1 = (i1 >> 2) * (KA * 2) + (((i1 & 3) ^ ((i1 >> 3) & 3)) * 16);
  int l0 = i0 * 16, l1 = i1 * 16;

  // Fragment read slot: (ln4 ^ ((row>>1)&3))*16; (row>>1)&3 == (lane>>1)&3.
  int rslot = ((ln4 ^ ((lane >> 1) & 3)) * 16);

  f32x4 acc[8][4] = {};
  half8 aF[8], bF[4];

  // prologue: stage ring slots 0,1,2 (tiles 0,1,2); drain tile 0; publish.
  STAGE4(0, 0); STAGE4(1, 1); STAGE4(2, 2);
  VMW8; BAR; SCHED0;

  // steady state: t = 0..127 (all stage t+3, guard vmcnt(8))
#pragma unroll 1
  for (int t4 = 0; t4 < NT - 4; t4 += 4) {
    TILE_FULL(0); TILE_FULL(1); TILE_FULL(2); TILE_FULL(3);
  }

  // peeled tail t = 128..131 (ring slots 0..3)
  { READS(0); STAGE4(131, 3); LGKM0; MFMA32; VMW8; BAR; SCHED0; }  // t=128
  { READS(1); LGKM0; MFMA32; VMW4; BAR; SCHED0; }                  // t=129
  { READS(2); LGKM0; MFMA32; VMW0; BAR; SCHED0; }                  // t=130
  { READS(3); LGKM0; MFMA32; }                                     // t=131

  // epilogue: + bias, fp32 store. C/D: col = lane&15, row = (lane>>4)*4 + reg
#pragma unroll
  for (int ni = 0; ni < 4; ++ni) {
    int n = n0 + wn + ni * 16 + ln15;
    float bz = bias[n];
#pragma unroll
    for (int mi = 0; mi < 8; ++mi) {
      f32x4 v = acc[mi][ni];
      int mb = m0 + wm + mi * 16 + ln4 * 4;
#pragma unroll
      for (int jj = 0; jj < 4; ++jj)
        out[(size_t)(mb + jj) * N_TOT + n] = v[jj] + bz;
    }
  }
}

// ---------------- fallback GEMM (reg-staged f32->f16, 128x128, low ws)
__global__ __launch_bounds__(256) void gemm_fallback(
    const float* __restrict__ x, const float* __restrict__ wgt,
    const float* __restrict__ midw, const float* __restrict__ lorabf,
    const float* __restrict__ bias, float* __restrict__ out) {
  __shared__ _Float16 As[128 * 64];
  __shared__ _Float16 Bs[128 * 64];
  int tid = threadIdx.x, lane = tid & 63, w = tid >> 6;
  int mt = blockIdx.x & 63, nt = blockIdx.x >> 6;
  int m0 = mt << 7, n0 = nt << 7;
  int wm = (w >> 1) * 64, wn = (w & 1) * 64;
  f32x4 acc[4][4] = {};
  for (int ks = 0; ks < 66; ++ks) {
    int k0 = ks * 64;
    const float *asrc, *bsrc; size_t astr, bstr; int ac, bc;
    if (ks < 64) { asrc = x;    astr = K_IN; ac = k0;        bsrc = wgt;    bstr = K_IN; bc = k0; }
    else         { asrc = midw; astr = 128;  ac = k0 - K_IN; bsrc = lorabf; bstr = 128;  bc = k0 - K_IN; }
#pragma unroll
    for (int it = 0; it < 8; ++it) {
      int idx = tid + it * 256;
      int r = idx >> 4, c4 = idx & 15;
      float4 fa = *(const float4*)(asrc + (size_t)(m0 + r) * astr + ac + c4 * 4);
      cvt_store4(As + r * 64 + c4 * 4, fa);
      float4 fb = *(const float4*)(bsrc + (size_t)(n0 + r) * bstr + bc + c4 * 4);
      cvt_store4(Bs + r * 64 + c4 * 4, fb);
    }
    __syncthreads();
#pragma unroll
    for (int kk = 0; kk < 2; ++kk) {
      half8 a[4], bf[4];
#pragma unroll
      for (int mi = 0; mi < 4; ++mi)
        a[mi] = *(const half8*)(As + (wm + mi * 16 + (lane & 15)) * 64 + kk * 32 + (lane >> 4) * 8);
#pragma unroll
      for (int ni = 0; ni < 4; ++ni)
        bf[ni] = *(const half8*)(Bs + (wn + ni * 16 + (lane & 15)) * 64 + kk * 32 + (lane >> 4) * 8);
#pragma unroll
      for (int mi = 0; mi < 4; ++mi)
#pragma unroll
        for (int ni = 0; ni < 4; ++ni)
          acc[mi][ni] = __builtin_amdgcn_mfma_f32_16x16x32_f16(a[mi], bf[ni], acc[mi][ni], 0, 0, 0);
    }
    __syncthreads();
  }
#pragma unroll
  for (int ni = 0; ni < 4; ++ni) {
    int n = n0 + wn + ni * 16 + (lane & 15);
    float bz = bias[n];
#pragma unroll
    for (int mi = 0; mi < 4; ++mi) {
      f32x4 v = acc[mi][ni];
      int mbase = m0 + wm + mi * 16 + (lane >> 4) * 4;
#pragma unroll
      for (int jj = 0; jj < 4; ++jj)
        out[(size_t)(mbase + jj) * N_TOT + n] = v[jj] + bz;
    }
  }
}

extern "C" void kernel_launch(void* const* d_in, const int* in_sizes, int n_in,
                              void* d_out, int out_size, void* d_ws, size_t ws_size,
                              hipStream_t stream) {
  const float* x      = (const float*)d_in[0];
  const float* router = (const float*)d_in[1];
  const float* wgt    = (const float*)d_in[2];
  const float* bias   = (const float*)d_in[3];
  const float* loraA  = (const float*)d_in[4];
  const float* loraB  = (const float*)d_in[5];
  float* out = (float*)d_out;
  char* ws = (char*)d_ws;

  const size_t XAUG_B = (size_t)M_TOT * KA * 2;    // 69,206,016
  const size_t WAUG_B = (size_t)N_TOT * KA * 2;    // 34,603,008
  const size_t LAH_B  = (size_t)128 * K_IN * 2;    //  1,048,576
  const size_t MIDW_B = (size_t)M_TOT * 128 * 4;   //  4,194,304
  bool fast = ws_size >= XAUG_B + WAUG_B + LAH_B;

  if (fast) {
    _Float16* Xa  = (_Float16*)ws;
    _Float16* Wa  = (_Float16*)(ws + XAUG_B);
    _Float16* lAh = (_Float16*)(ws + XAUG_B + WAUG_B);
    convert_f32_f16_t<12, KA><<<2048, 256, 0, stream>>>(x,   Xa, M_TOT * K_IN / 8);
    convert_f32_f16_t<12, KA><<<2048, 256, 0, stream>>>(wgt, Wa, N_TOT * K_IN / 8);
    convert_f32_f16_t<12, 4096><<<256, 256, 0, stream>>>(loraA, lAh, 128 * K_IN / 8);
    wtail_gather_f16<<<2048, 256, 0, stream>>>(loraB, Wa);
    mid2_kernel<<<256, 256, 0, stream>>>(Xa, lAh, router);
    gemm256<<<512, 512, 0, stream>>>(Xa, Wa, bias, out);
  } else {
    float* midw   = (float*)ws;
    float* lorabf = (float*)(ws + MIDW_B);
    lorabf_gather_f32<<<2048, 256, 0, stream>>>(loraB, lorabf);
    mid_kernel<<<256, 256, 0, stream>>>(x, loraA, router, midw);
    gemm_fallback<<<2048, 256, 0, stream>>>(x, wgt, midw, lorabf, bias, out);
  }
}